// Round 3
// baseline (1038.037 us; speedup 1.0000x reference)
//
#include <hip/hip_runtime.h>
#include <math.h>

typedef __attribute__((ext_vector_type(8))) short bf16x8;
typedef __attribute__((ext_vector_type(4))) float f32x4;
typedef __attribute__((ext_vector_type(4))) unsigned short u16x4;

#define NB 64
#define NS 4096
#define NH 512
#define NE 1024
#define APITCH 80  // 64B of bf16 K-data + 16B pad: quarter-wave conflict-free b128 reads

__device__ __forceinline__ unsigned short f2bf(float f) {
  unsigned int u = __float_as_uint(f);
  u += 0x7fffu + ((u >> 16) & 1u);
  return (unsigned short)(u >> 16);
}

__device__ __forceinline__ float fast_tanh(float x) {
  // tanh(x) = 1 - 2/(exp(2x)+1); exp(2x) = 2^(2*log2e*x). |err| ~1e-6 abs.
  float e = __expf(2.0f * x);
  return 1.0f - 2.0f * __builtin_amdgcn_rcpf(e + 1.0f);
}

// ---- pack W (f32 [512][1024]) into MFMA B-fragment order, bf16 ----
// chunk c = ((w*32 + kb)*4 + ni); lane l's 16B = W[w*64+ni*16+(l&15)][kb*32+(l>>4)*8 .. +7]
__global__ __launch_bounds__(256) void prep_b_kernel(const float* __restrict__ W,
                                                     unsigned short* __restrict__ Bp) {
  const int t = blockIdx.x * 256 + threadIdx.x;  // 0..65535
  const int lane = t & 63;
  const int ni = (t >> 6) & 3;
  const int kb = (t >> 8) & 31;
  const int w = t >> 13;
  const int col = w * 64 + ni * 16 + (lane & 15);
  const int k0 = kb * 32 + (lane >> 4) * 8;
  const float* src = W + col * NE + k0;
  float4 a = *(const float4*)src;
  float4 b = *(const float4*)(src + 4);
  union { bf16x8 v; unsigned short u[8]; } p;
  p.u[0] = f2bf(a.x); p.u[1] = f2bf(a.y); p.u[2] = f2bf(a.z); p.u[3] = f2bf(a.w);
  p.u[4] = f2bf(b.x); p.u[5] = f2bf(b.y); p.u[6] = f2bf(b.z); p.u[7] = f2bf(b.w);
  *(bf16x8*)(Bp + (long long)t * 8) = p.v;
}

// ---- prep: dec[b,h] = decoder_output[b,:] . W_s_w[h,:] + W_s_b[h] + W_h_b[h] ----
__global__ __launch_bounds__(512) void prep_dec_kernel(const float* __restrict__ dec,
                                                       const float* __restrict__ Wsw,
                                                       const float* __restrict__ Wsb,
                                                       const float* __restrict__ Whb,
                                                       float* __restrict__ decb) {
  int b = blockIdx.x;
  int h = threadIdx.x;
  const float4* dr = (const float4*)(dec + b * NH);
  const float4* wr = (const float4*)(Wsw + h * NH);
  float sum = Wsb[h] + Whb[h];
#pragma unroll 8
  for (int i = 0; i < NH / 4; ++i) {
    float4 a = dr[i], w = wr[i];
    sum += a.x * w.x + a.y * w.y + a.z * w.z + a.w * w.w;
  }
  decb[b * NH + h] = sum;
}

// ---- main: enc-proj GEMM (bf16 MFMA) + bias + tanh + v-dot -> scores ----
// BM=64, BN=512, BK=32, 512 thr / 8 waves, 2 blocks/CU.
// A: LDS double-buffered, raw-reg prefetch 3 steps deep from HBM; pack->LDS AFTER MFMAs.
// B: straight to VGPRs from L2 (pre-packed frag order), 1 step ahead.
// Sync: raw s_barrier + lgkmcnt(0) only -> vmem prefetches stay in flight (T4).
__global__ __launch_bounds__(512, 4) void fused_main(const float* __restrict__ enc,
                                                     const unsigned short* __restrict__ Bp,
                                                     const float* __restrict__ decb,
                                                     const float* __restrict__ vw,
                                                     float* __restrict__ scores) {
  __shared__ char As[2][64 * APITCH];  // 2 x 5 KB
  __shared__ float ssc[64];

  const int tid = threadIdx.x;
  const int lane = tid & 63;
  const int wave = tid >> 6;
  const int r15 = lane & 15;
  const int c4 = lane >> 4;
  const long long m0 = (long long)blockIdx.x * 64;

  if (tid < 64) ssc[tid] = 0.0f;

  // A staging: thread -> (row = tid>>3, k-granule = tid&7) loads 4 f32 (coalesced 128B/row)
  const int arow = tid >> 3;
  const int agk = tid & 7;
  const float* aload = enc + (m0 + arow) * NE + agk * 4;
  char* const awr0 = &As[0][0] + arow * APITCH + agk * 8;
  char* const awr1 = &As[1][0] + arow * APITCH + agk * 8;

  // B packed base for this wave: chunk ((wave*32+kb)*4+ni)*512 shorts + lane*8
  const unsigned short* const bb = Bp + (long long)wave * 32 * 2048 + lane * 8;

  f32x4 acc[4][4];
#pragma unroll
  for (int mi = 0; mi < 4; ++mi)
#pragma unroll
    for (int ni = 0; ni < 4; ++ni) {
      f32x4 z = {0.f, 0.f, 0.f, 0.f};
      acc[mi][ni] = z;
    }

  // prologue: A(0) -> LDS buf0; B(0) -> regs; A(1),A(2) raw -> regs (3-deep w/ loop load)
  {
    float4 a0 = *(const float4*)(aload);
    u16x4 pw;
    pw.x = f2bf(a0.x); pw.y = f2bf(a0.y); pw.z = f2bf(a0.z); pw.w = f2bf(a0.w);
    *(u16x4*)awr0 = pw;
  }
  bf16x8 bcur[4];
#pragma unroll
  for (int ni = 0; ni < 4; ++ni) bcur[ni] = *(const bf16x8*)(bb + ni * 512);
  float4 A0 = *(const float4*)(aload + 32);   // data for step 1
  float4 A1 = *(const float4*)(aload + 64);   // data for step 2
  __syncthreads();

#pragma unroll 2
  for (int t = 0; t < 32; ++t) {
    const char* Ac = &As[t & 1][0];
    bf16x8 bnxt[4];
    float4 Anew;
    if (t < 31) {  // B frags for step t+1 (L2, coalesced 1KB wave-loads)
      const unsigned short* bp = bb + (t + 1) * 2048;
#pragma unroll
      for (int ni = 0; ni < 4; ++ni) bnxt[ni] = *(const bf16x8*)(bp + ni * 512);
    }
    if (t < 29) Anew = *(const float4*)(aload + (t + 3) * 32);  // raw A, 3 steps ahead (HBM)

    bf16x8 af[4];
#pragma unroll
    for (int mi = 0; mi < 4; ++mi)
      af[mi] = *(const bf16x8*)(Ac + (mi * 16 + r15) * APITCH + c4 * 16);
    __builtin_amdgcn_s_setprio(1);
#pragma unroll
    for (int mi = 0; mi < 4; ++mi)
#pragma unroll
      for (int ni = 0; ni < 4; ++ni)
        acc[mi][ni] = __builtin_amdgcn_mfma_f32_16x16x32_bf16(af[mi], bcur[ni],
                                                              acc[mi][ni], 0, 0, 0);
    __builtin_amdgcn_s_setprio(0);
    if (t < 31) {  // pack A(t+1) -> opposite LDS buffer, AFTER compute (stall-tolerant)
      u16x4 pw;
      pw.x = f2bf(A0.x); pw.y = f2bf(A0.y); pw.z = f2bf(A0.z); pw.w = f2bf(A0.w);
      *(u16x4*)((t & 1) ? awr0 : awr1) = pw;
    }
    // all LDS ops (frag reads above, write for t+1) must land before waves cross
    asm volatile("s_waitcnt lgkmcnt(0)" ::: "memory");
    __builtin_amdgcn_sched_barrier(0);
    __builtin_amdgcn_s_barrier();
    if (t < 31) {
#pragma unroll
      for (int ni = 0; ni < 4; ++ni) bcur[ni] = bnxt[ni];
      A0 = A1;
      A1 = Anew;
    }
  }

  // epilogue: x = tanh(acc + dec[b,h]); score += v[h]*x
  // C/D layout: col = lane&15 (n), row = (lane>>4)*4 + j (m)
  const int bidx = (int)(m0 >> 12);  // blockIdx / 64
  const float* decrow = decb + bidx * NH;
  float part[4][4];
#pragma unroll
  for (int mi = 0; mi < 4; ++mi)
#pragma unroll
    for (int j = 0; j < 4; ++j) part[mi][j] = 0.f;

#pragma unroll
  for (int ni = 0; ni < 4; ++ni) {
    int col = (wave << 6) + ni * 16 + r15;
    float vc = vw[col];
    float dc = decrow[col];
#pragma unroll
    for (int mi = 0; mi < 4; ++mi)
#pragma unroll
      for (int j = 0; j < 4; ++j)
        part[mi][j] += vc * fast_tanh(acc[mi][ni][j] + dc);
  }
#pragma unroll
  for (int off = 1; off < 16; off <<= 1)
#pragma unroll
    for (int mi = 0; mi < 4; ++mi)
#pragma unroll
      for (int j = 0; j < 4; ++j)
        part[mi][j] += __shfl_xor(part[mi][j], off, 64);

  if (r15 == 0) {
#pragma unroll
    for (int mi = 0; mi < 4; ++mi)
#pragma unroll
      for (int j = 0; j < 4; ++j)
        atomicAdd(&ssc[mi * 16 + c4 * 4 + j], part[mi][j]);
  }
  __syncthreads();
  if (tid < 64) scores[m0 + tid] = ssc[tid];
}

// ---- masked softmax over S per batch row ----
__global__ __launch_bounds__(1024) void softmax_kernel(const float* __restrict__ scores,
                                                       const int* __restrict__ mask,
                                                       float* __restrict__ out) {
  __shared__ float rmax[16];
  __shared__ float rsum[16];
  const int b = blockIdx.x;
  const int t = threadIdx.x;
  const int wid = t >> 6;
  const int ln = t & 63;
  const int base = b * NS;

  float s[4];
  int mk[4];
  float mx = -INFINITY;
#pragma unroll
  for (int i = 0; i < 4; ++i) {
    int idx = t + i * 1024;
    s[i] = scores[base + idx];
    mk[i] = mask[base + idx];
    if (mk[i]) mx = fmaxf(mx, s[i]);
  }
#pragma unroll
  for (int off = 1; off < 64; off <<= 1) mx = fmaxf(mx, __shfl_xor(mx, off, 64));
  if (ln == 0) rmax[wid] = mx;
  __syncthreads();
  float m2 = -INFINITY;
#pragma unroll
  for (int i = 0; i < 16; ++i) m2 = fmaxf(m2, rmax[i]);

  float e[4];
  float sum = 0.f;
#pragma unroll
  for (int i = 0; i < 4; ++i) {
    e[i] = mk[i] ? expf(s[i] - m2) : 0.f;
    sum += e[i];
  }
#pragma unroll
  for (int off = 1; off < 64; off <<= 1) sum += __shfl_xor(sum, off, 64);
  if (ln == 0) rsum[wid] = sum;
  __syncthreads();
  float tot = 0.f;
#pragma unroll
  for (int i = 0; i < 16; ++i) tot += rsum[i];
  float inv = 1.0f / tot;
#pragma unroll
  for (int i = 0; i < 4; ++i) {
    int idx = t + i * 1024;
    out[base + idx] = e[i] * inv;
  }
}

extern "C" void kernel_launch(void* const* d_in, const int* in_sizes, int n_in,
                              void* d_out, int out_size, void* d_ws, size_t ws_size,
                              hipStream_t stream) {
  const float* dec = (const float*)d_in[0];   // [64,512]
  const float* enc = (const float*)d_in[1];   // [64,4096,1024]
  const int* mask = (const int*)d_in[2];      // [64,4096]
  const float* Whw = (const float*)d_in[3];   // [512,1024]
  const float* Whb = (const float*)d_in[4];   // [512]
  const float* Wsw = (const float*)d_in[5];   // [512,512]
  const float* Wsb = (const float*)d_in[6];   // [512]
  const float* vw = (const float*)d_in[7];    // [1,512]
  float* out = (float*)d_out;                 // [64,4096]

  unsigned short* Bp = (unsigned short*)d_ws;                         // 1 MB packed W
  float* decb = (float*)((char*)d_ws + (1 << 20));                    // 128 KB
  float* scoresb = (float*)((char*)d_ws + (1 << 20) + (128 << 10));   // 1 MB

  prep_b_kernel<<<dim3(256), dim3(256), 0, stream>>>(Whw, Bp);
  prep_dec_kernel<<<dim3(64), dim3(512), 0, stream>>>(dec, Wsw, Wsb, Whb, decb);
  fused_main<<<dim3(4096), dim3(512), 0, stream>>>(enc, Bp, decb, vw, scoresb);
  softmax_kernel<<<dim3(64), dim3(1024), 0, stream>>>(scoresb, mask, out);
}

// Round 4
// 449.002 us; speedup vs baseline: 2.3119x; 2.3119x over previous
//
#include <hip/hip_runtime.h>
#include <math.h>

typedef __attribute__((ext_vector_type(8))) short bf16x8;
typedef __attribute__((ext_vector_type(4))) float f32x4;
typedef __attribute__((ext_vector_type(4))) unsigned short u16x4;

#define NB 64
#define NS 4096
#define NH 512
#define NE 1024

__device__ __forceinline__ unsigned short f2bf(float f) {
  unsigned int u = __float_as_uint(f);
  u += 0x7fffu + ((u >> 16) & 1u);
  return (unsigned short)(u >> 16);
}

__device__ __forceinline__ float fast_tanh(float x) {
  float e = __expf(2.0f * x);
  return 1.0f - 2.0f * __builtin_amdgcn_rcpf(e + 1.0f);
}

// ---- pack W (f32 [512][1024]) into MFMA B-fragment order, bf16 ----
// chunk c = ((w*32 + kb)*4 + ni); lane l's 16B = W[w*64+ni*16+(l&15)][kb*32+(l>>4)*8 .. +7]
__global__ __launch_bounds__(256) void prep_b_kernel(const float* __restrict__ W,
                                                     unsigned short* __restrict__ Bp) {
  const int t = blockIdx.x * 256 + threadIdx.x;  // 0..65535
  const int lane = t & 63;
  const int ni = (t >> 6) & 3;
  const int kb = (t >> 8) & 31;
  const int w = t >> 13;
  const int col = w * 64 + ni * 16 + (lane & 15);
  const int k0 = kb * 32 + (lane >> 4) * 8;
  const float* src = W + col * NE + k0;
  float4 a = *(const float4*)src;
  float4 b = *(const float4*)(src + 4);
  union { bf16x8 v; unsigned short u[8]; } p;
  p.u[0] = f2bf(a.x); p.u[1] = f2bf(a.y); p.u[2] = f2bf(a.z); p.u[3] = f2bf(a.w);
  p.u[4] = f2bf(b.x); p.u[5] = f2bf(b.y); p.u[6] = f2bf(b.z); p.u[7] = f2bf(b.w);
  *(bf16x8*)(Bp + (long long)t * 8) = p.v;
}

// ---- prep: dec[b,h] = decoder_output[b,:] . W_s_w[h,:] + W_s_b[h] + W_h_b[h] ----
__global__ __launch_bounds__(512) void prep_dec_kernel(const float* __restrict__ dec,
                                                       const float* __restrict__ Wsw,
                                                       const float* __restrict__ Wsb,
                                                       const float* __restrict__ Whb,
                                                       float* __restrict__ decb) {
  int b = blockIdx.x;
  int h = threadIdx.x;
  const float4* dr = (const float4*)(dec + b * NH);
  const float4* wr = (const float4*)(Wsw + h * NH);
  float sum = Wsb[h] + Whb[h];
#pragma unroll 8
  for (int i = 0; i < NH / 4; ++i) {
    float4 a = dr[i], w = wr[i];
    sum += a.x * w.x + a.y * w.y + a.z * w.z + a.w * w.w;
  }
  decb[b * NH + h] = sum;
}

// ---- main: enc-proj GEMM (bf16 MFMA) + bias + tanh + v-dot -> scores ----
// BM=64, BN=512, BK=32, 512 thr / 8 waves, target 2 blocks/CU (<=128 total regs).
// A: f32 via global_load_lds into 3 rotating 8KB LDS buffers, issued 2 iters ahead;
//    granule XOR-swizzle on BOTH global source and LDS reads (G21); f32->bf16 via
//    v_cvt_pk_bf16_f32 at frag-read time.
// B: pre-packed frag order, global->VGPR (bcur) reloaded right after MFMA cluster.
// Sync: counted vmcnt (never 0) + lgkmcnt(0) + raw s_barrier per iter (T4).
__global__ __launch_bounds__(512, 4) void fused_main(const float* __restrict__ enc,
                                                     const unsigned short* __restrict__ Bp,
                                                     const float* __restrict__ decb,
                                                     const float* __restrict__ vw,
                                                     float* __restrict__ scores) {
  __shared__ __align__(16) float As[3][2048];  // 3 x 8KB: 64 rows x 32 f32 (128B), swizzled
  __shared__ float ssc[64];

  const int tid = threadIdx.x;
  const int lane = tid & 63;
  const int wave = tid >> 6;
  const int r15 = lane & 15;
  const int c4 = lane >> 4;
  const long long m0 = (long long)blockIdx.x * 64;

  if (tid < 64) ssc[tid] = 0.0f;

  // DMA staging: wave w lane l writes LDS bytes w*1024 + l*16 (linear) = row w*8+(l>>3),
  // phys granule l&7. Source must hold logical granule (l&7)^(row&7) = (l&7)^(l>>3).
  const int grow = wave * 8 + (lane >> 3);
  const int ggran = (lane & 7) ^ (lane >> 3);
  const float* gsrc = enc + (m0 + grow) * NE + ggran * 4;
  const unsigned ldsoff = wave * 1024;  // bytes within each buffer

  // read-side: logical granule g at row r lives at phys g^(r&7); row = mi*16+r15 -> r&7=lane&7
  const int rowb = r15 * 128;
  const int pg0 = (((c4 << 1) | 0) ^ (lane & 7)) << 4;
  const int pg1 = (((c4 << 1) | 1) ^ (lane & 7)) << 4;

  const unsigned short* const bb = Bp + (long long)wave * 32 * 2048 + lane * 8;

  f32x4 acc[4][4];
#pragma unroll
  for (int mi = 0; mi < 4; ++mi)
#pragma unroll
    for (int ni = 0; ni < 4; ++ni) {
      f32x4 z = {0.f, 0.f, 0.f, 0.f};
      acc[mi][ni] = z;
    }

  // prologue: B(0) -> bcur; A(0) -> buf0, A(1) -> buf1 (async DMA)
  bf16x8 bcur[4];
#pragma unroll
  for (int ni = 0; ni < 4; ++ni) bcur[ni] = *(const bf16x8*)(bb + ni * 512);
  __builtin_amdgcn_global_load_lds((const unsigned int*)gsrc,
                                   (unsigned int*)((char*)&As[0][0] + ldsoff), 16, 0, 0);
  __builtin_amdgcn_global_load_lds((const unsigned int*)(gsrc + 32),
                                   (unsigned int*)((char*)&As[1][0] + ldsoff), 16, 0, 0);
  asm volatile("s_waitcnt vmcnt(1)" ::: "memory");  // A(0) landed (A(1) in flight)
  __builtin_amdgcn_s_barrier();

#pragma unroll
  for (int t = 0; t < 32; ++t) {
    const char* Ab = (const char*)&As[t % 3][0];
    // frag read + convert: 8x ds_read_b128 (f32) -> 16x v_cvt_pk_bf16_f32
    bf16x8 af[4];
#pragma unroll
    for (int mi = 0; mi < 4; ++mi) {
      f32x4 lo = *(const f32x4*)(Ab + mi * 2048 + rowb + pg0);
      f32x4 hi = *(const f32x4*)(Ab + mi * 2048 + rowb + pg1);
      union { unsigned int u[4]; bf16x8 v; } pk;
      asm("v_cvt_pk_bf16_f32 %0, %1, %2" : "=v"(pk.u[0]) : "v"(lo.x), "v"(lo.y));
      asm("v_cvt_pk_bf16_f32 %0, %1, %2" : "=v"(pk.u[1]) : "v"(lo.z), "v"(lo.w));
      asm("v_cvt_pk_bf16_f32 %0, %1, %2" : "=v"(pk.u[2]) : "v"(hi.x), "v"(hi.y));
      asm("v_cvt_pk_bf16_f32 %0, %1, %2" : "=v"(pk.u[3]) : "v"(hi.z), "v"(hi.w));
      af[mi] = pk.v;
    }
    __builtin_amdgcn_s_setprio(1);
#pragma unroll
    for (int mi = 0; mi < 4; ++mi)
#pragma unroll
      for (int ni = 0; ni < 4; ++ni)
        acc[mi][ni] = __builtin_amdgcn_mfma_f32_16x16x32_bf16(af[mi], bcur[ni],
                                                              acc[mi][ni], 0, 0, 0);
    __builtin_amdgcn_s_setprio(0);
    // B(t+1) -> bcur (L2; WAR on MFMA keeps these after the cluster)
    if (t < 31) {
      const unsigned short* bp = bb + (t + 1) * 2048;
#pragma unroll
      for (int ni = 0; ni < 4; ++ni) bcur[ni] = *(const bf16x8*)(bp + ni * 512);
    }
    // A(t+2) DMA (issued AFTER B loads: FIFO lets pre-MFMA wait drain only B)
    if (t < 30)
      __builtin_amdgcn_global_load_lds((const unsigned int*)(gsrc + (t + 2) * 32),
                                       (unsigned int*)((char*)&As[(t + 2) % 3][0] + ldsoff),
                                       16, 0, 0);
    if (t < 31) {
      // ensure A(t+1) landed; keep B(t+1)x4 (+A(t+2)) in flight across the barrier
      if (t < 30) asm volatile("s_waitcnt vmcnt(5)" ::: "memory");
      else        asm volatile("s_waitcnt vmcnt(4)" ::: "memory");
      asm volatile("s_waitcnt lgkmcnt(0)" ::: "memory");
      __builtin_amdgcn_sched_barrier(0);
      __builtin_amdgcn_s_barrier();
    }
  }

  // epilogue: x = tanh(acc + dec[b,h]); score += v[h]*x
  // C/D layout: col = lane&15 (n), row = (lane>>4)*4 + j (m)
  const int bidx = (int)(m0 >> 12);  // blockIdx / 64
  const float* decrow = decb + bidx * NH;
  float part[4][4];
#pragma unroll
  for (int mi = 0; mi < 4; ++mi)
#pragma unroll
    for (int j = 0; j < 4; ++j) part[mi][j] = 0.f;

#pragma unroll
  for (int ni = 0; ni < 4; ++ni) {
    int col = (wave << 6) + ni * 16 + r15;
    float vc = vw[col];
    float dc = decrow[col];
#pragma unroll
    for (int mi = 0; mi < 4; ++mi)
#pragma unroll
      for (int j = 0; j < 4; ++j)
        part[mi][j] += vc * fast_tanh(acc[mi][ni][j] + dc);
  }
#pragma unroll
  for (int off = 1; off < 16; off <<= 1)
#pragma unroll
    for (int mi = 0; mi < 4; ++mi)
#pragma unroll
      for (int j = 0; j < 4; ++j)
        part[mi][j] += __shfl_xor(part[mi][j], off, 64);

  if (r15 == 0) {
#pragma unroll
    for (int mi = 0; mi < 4; ++mi)
#pragma unroll
      for (int j = 0; j < 4; ++j)
        atomicAdd(&ssc[mi * 16 + c4 * 4 + j], part[mi][j]);
  }
  __syncthreads();
  if (tid < 64) scores[m0 + tid] = ssc[tid];
}

// ---- masked softmax over S per batch row ----
__global__ __launch_bounds__(1024) void softmax_kernel(const float* __restrict__ scores,
                                                       const int* __restrict__ mask,
                                                       float* __restrict__ out) {
  __shared__ float rmax[16];
  __shared__ float rsum[16];
  const int b = blockIdx.x;
  const int t = threadIdx.x;
  const int wid = t >> 6;
  const int ln = t & 63;
  const int base = b * NS;

  float s[4];
  int mk[4];
  float mx = -INFINITY;
#pragma unroll
  for (int i = 0; i < 4; ++i) {
    int idx = t + i * 1024;
    s[i] = scores[base + idx];
    mk[i] = mask[base + idx];
    if (mk[i]) mx = fmaxf(mx, s[i]);
  }
#pragma unroll
  for (int off = 1; off < 64; off <<= 1) mx = fmaxf(mx, __shfl_xor(mx, off, 64));
  if (ln == 0) rmax[wid] = mx;
  __syncthreads();
  float m2 = -INFINITY;
#pragma unroll
  for (int i = 0; i < 16; ++i) m2 = fmaxf(m2, rmax[i]);

  float e[4];
  float sum = 0.f;
#pragma unroll
  for (int i = 0; i < 4; ++i) {
    e[i] = mk[i] ? expf(s[i] - m2) : 0.f;
    sum += e[i];
  }
#pragma unroll
  for (int off = 1; off < 64; off <<= 1) sum += __shfl_xor(sum, off, 64);
  if (ln == 0) rsum[wid] = sum;
  __syncthreads();
  float tot = 0.f;
#pragma unroll
  for (int i = 0; i < 16; ++i) tot += rsum[i];
  float inv = 1.0f / tot;
#pragma unroll
  for (int i = 0; i < 4; ++i) {
    int idx = t + i * 1024;
    out[base + idx] = e[i] * inv;
  }
}

extern "C" void kernel_launch(void* const* d_in, const int* in_sizes, int n_in,
                              void* d_out, int out_size, void* d_ws, size_t ws_size,
                              hipStream_t stream) {
  const float* dec = (const float*)d_in[0];   // [64,512]
  const float* enc = (const float*)d_in[1];   // [64,4096,1024]
  const int* mask = (const int*)d_in[2];      // [64,4096]
  const float* Whw = (const float*)d_in[3];   // [512,1024]
  const float* Whb = (const float*)d_in[4];   // [512]
  const float* Wsw = (const float*)d_in[5];   // [512,512]
  const float* Wsb = (const float*)d_in[6];   // [512]
  const float* vw = (const float*)d_in[7];    // [1,512]
  float* out = (float*)d_out;                 // [64,4096]

  unsigned short* Bp = (unsigned short*)d_ws;                         // 1 MB packed W
  float* decb = (float*)((char*)d_ws + (1 << 20));                    // 128 KB
  float* scoresb = (float*)((char*)d_ws + (1 << 20) + (128 << 10));   // 1 MB

  prep_b_kernel<<<dim3(256), dim3(256), 0, stream>>>(Whw, Bp);
  prep_dec_kernel<<<dim3(64), dim3(512), 0, stream>>>(dec, Wsw, Wsb, Whb, decb);
  fused_main<<<dim3(4096), dim3(512), 0, stream>>>(enc, Bp, decb, vw, scoresb);
  softmax_kernel<<<dim3(64), dim3(1024), 0, stream>>>(scoresb, mask, out);
}